// Round 5
// baseline (137.826 us; speedup 1.0000x reference)
//
#include <hip/hip_runtime.h>
#include <math.h>

#define BB 8
#define CC 64
#define NN 4096
#define CI 8
#define GAMMA 0.1f
// exp(s/sqrt(8)) = exp2(s * log2(e)/sqrt(8)); folded into k at qkv time.
#define SCALE (1.44269504088896f * 0.35355339059327f)

typedef float v2f __attribute__((ext_vector_type(2)));
typedef float v4f __attribute__((ext_vector_type(4)));

__device__ __forceinline__ float fast_exp2(float x) {
    return __builtin_amdgcn_exp2f(x);
}

// Grid (NN/32, BB); block 256 = 8 i-groups x 32 n. Each block: 32-n tile, all i.
// Weights via b128 LDS broadcasts; q/v assembled in padded LDS tile then
// written as coalesced float4. kb[b][i][n] coalesced, pre-scaled by SCALE.
// Also zeros attab before the barrier.
__global__ __launch_bounds__(256) void qkv_kernel(
        const float* __restrict__ x,
        const float* __restrict__ Wq, const float* __restrict__ Wk,
        const float* __restrict__ Wv,
        float* __restrict__ qv, float* __restrict__ kb,
        float* __restrict__ attab) {
    __shared__ float sw[3 * CI * CC];   // 6 KB: Wq | Wk*SCALE | Wv
    __shared__ float sqv[32 * 20];      // 2.5 KB: [n_local][q0..7 v0..7 pad4]
    const int t = threadIdx.x;
    const int i  = t >> 5;          // 0..7
    const int nl = t & 31;          // 0..31
    const int b  = blockIdx.y;
    const int n0 = blockIdx.x * 32;

    for (int idx = t; idx < CI * CC; idx += 256) {
        sw[idx]                = Wq[idx];
        sw[CI * CC + idx]      = Wk[idx] * SCALE;
        sw[2 * CI * CC + idx]  = Wv[idx];
    }
    // zero attab: 294912 elems over 262144 threads (<=2 stores each)
    int lin = (blockIdx.y * (NN / 32) + blockIdx.x) * 256 + t;
    for (int idx = lin; idx < BB * 9 * NN; idx += BB * NN * CI) attab[idx] = 0.f;
    __syncthreads();

    const int n = n0 + nl;
    const float* xp = x + ((size_t)b * CC) * NN + n;
    const v4f* wq4 = (const v4f*)(sw + i * CC);
    const v4f* wk4 = (const v4f*)(sw + CI * CC + i * CC);
    const v4f* wv4 = (const v4f*)(sw + 2 * CI * CC + i * CC);
    float qa = 0.f, ka = 0.f, va = 0.f;
#pragma unroll 4
    for (int c4 = 0; c4 < CC / 4; ++c4) {
        v4f wq = wq4[c4], wk = wk4[c4], wv = wv4[c4];   // LDS broadcast b128
        float x0 = xp[(size_t)(c4 * 4 + 0) * NN];
        float x1 = xp[(size_t)(c4 * 4 + 1) * NN];
        float x2 = xp[(size_t)(c4 * 4 + 2) * NN];
        float x3 = xp[(size_t)(c4 * 4 + 3) * NN];
        qa = fmaf(wq.x, x0, qa); ka = fmaf(wk.x, x0, ka); va = fmaf(wv.x, x0, va);
        qa = fmaf(wq.y, x1, qa); ka = fmaf(wk.y, x1, ka); va = fmaf(wv.y, x1, va);
        qa = fmaf(wq.z, x2, qa); ka = fmaf(wk.z, x2, ka); va = fmaf(wv.z, x2, va);
        qa = fmaf(wq.w, x3, qa); ka = fmaf(wk.w, x3, ka); va = fmaf(wv.w, x3, va);
    }
    kb[((size_t)b * CI + i) * NN + n] = ka;   // coalesced (128B per i-group)
    sqv[nl * 20 + i]     = qa;
    sqv[nl * 20 + 8 + i] = va;
    __syncthreads();
    if (t < 128) {
        int w = t * 4;
        int nn = w >> 4, p = w & 15;
        v4f val = *(const v4f*)(sqv + nn * 20 + p);
        *(v4f*)(qv + ((size_t)b * NN + n0 + nn) * 16 + p) = val;
    }
}

// Attention core. |scores| < ~2 so exp without max-subtraction is safe
// (softmax shift-invariant): att[n,m] = e(s_nm)/sum_n e(s_nm).
// R5: q/v are WAVE-UNIFORM per n -> read via uniform __restrict pointer
// (compiles to s_load / broadcast L1 hit). No LDS staging, no barrier,
// LDS pipe idle; inner loop is pure VALU (v_pk_fma_f32 takes the SGPR pair).
// Grid (8 m-tiles, 32 n-chunks, B) = 2048 blocks = 8 waves/SIMD.
// attab: [b][9][N], rows 0..7 = sum_n e*v_i, row 8 = sum_n e.
#define MT 2
#define NCHUNK 128
__global__ __launch_bounds__(256) void att_kernel(
        const float* __restrict__ qv, const float* __restrict__ kb,
        float* __restrict__ attab) {
    const int t = threadIdx.x;
    const int b = blockIdx.z;
    const int n0 = blockIdx.y * NCHUNK;
    const int m0 = blockIdx.x * (256 * MT);

    v2f kr[MT][4];
    int mm[MT];
#pragma unroll
    for (int j = 0; j < MT; ++j) {
        int m = m0 + t + 256 * j;
        mm[j] = m;
#pragma unroll
        for (int i = 0; i < 4; ++i) {
            float k0 = kb[((size_t)b * CI + 2 * i) * NN + m];
            float k1 = kb[((size_t)b * CI + 2 * i + 1) * NN + m];
            kr[j][i] = (v2f){k0, k1};
        }
    }

    v2f acc[MT][4];
    float es[MT];
#pragma unroll
    for (int j = 0; j < MT; ++j) {
        es[j] = 0.f;
#pragma unroll
        for (int i = 0; i < 4; ++i) acc[j][i] = (v2f){0.f, 0.f};
    }

    const float* qbase = qv + ((size_t)b * NN + n0) * 16;   // uniform
#pragma unroll 2
    for (int n = 0; n < NCHUNK; ++n) {
        const float* p = qbase + n * 16;        // uniform addr -> scalar load
        v4f qa = *(const v4f*)(p);
        v4f qb = *(const v4f*)(p + 4);
        v4f va = *(const v4f*)(p + 8);
        v4f vb = *(const v4f*)(p + 12);
        v2f q01 = {qa.x, qa.y}, q23 = {qa.z, qa.w};
        v2f q45 = {qb.x, qb.y}, q67 = {qb.z, qb.w};
        v2f v01 = {va.x, va.y}, v23 = {va.z, va.w};
        v2f v45 = {vb.x, vb.y}, v67 = {vb.z, vb.w};
#pragma unroll
        for (int j = 0; j < MT; ++j) {
            v2f s2 = q01 * kr[j][0];
            s2 = __builtin_elementwise_fma(q23, kr[j][1], s2);
            s2 = __builtin_elementwise_fma(q45, kr[j][2], s2);
            s2 = __builtin_elementwise_fma(q67, kr[j][3], s2);
            float e = fast_exp2(s2.x + s2.y);
            es[j] += e;
            v2f e2 = {e, e};
            acc[j][0] = __builtin_elementwise_fma(e2, v01, acc[j][0]);
            acc[j][1] = __builtin_elementwise_fma(e2, v23, acc[j][1]);
            acc[j][2] = __builtin_elementwise_fma(e2, v45, acc[j][2]);
            acc[j][3] = __builtin_elementwise_fma(e2, v67, acc[j][3]);
        }
    }

#pragma unroll
    for (int j = 0; j < MT; ++j) {
        float* ap = attab + (size_t)b * 9 * NN + mm[j];
#pragma unroll
        for (int i = 0; i < 4; ++i) {
            atomicAdd(ap + (size_t)(2 * i) * NN, acc[j][i].x);
            atomicAdd(ap + (size_t)(2 * i + 1) * NN, acc[j][i].y);
        }
        atomicAdd(ap + (size_t)8 * NN, es[j]);
    }
}

// Grid (NN/1024, CC, BB); block 256. Thread (b, c, m0): 4 m-columns via float4.
// Wout row block-uniform -> scalar loads; all vmem 16B coalesced.
__global__ __launch_bounds__(256) void out_kernel(
        const float* __restrict__ x, const float* __restrict__ Wout,
        const float* __restrict__ attab, float* __restrict__ out) {
    const int t = threadIdx.x;
    const int c = blockIdx.y;
    const int b = blockIdx.z;
    const int m = (blockIdx.x * 256 + t) * 4;
    const float* ap = attab + (size_t)b * 9 * NN + m;
    v4f sum = *(const v4f*)(ap + (size_t)8 * NN);
    v4f s = {0.f, 0.f, 0.f, 0.f};
#pragma unroll
    for (int i = 0; i < CI; ++i) {
        float w = Wout[c * CI + i];                 // uniform -> s_load
        v4f a = *(const v4f*)(ap + (size_t)i * NN);
        s.x = fmaf(w, a.x, s.x);
        s.y = fmaf(w, a.y, s.y);
        s.z = fmaf(w, a.z, s.z);
        s.w = fmaf(w, a.w, s.w);
    }
    size_t o = ((size_t)b * CC + c) * NN + m;
    v4f xv = *(const v4f*)(x + o);
    v4f r;
    r.x = xv.x + GAMMA * (s.x / sum.x);
    r.y = xv.y + GAMMA * (s.y / sum.y);
    r.z = xv.z + GAMMA * (s.z / sum.z);
    r.w = xv.w + GAMMA * (s.w / sum.w);
    *(v4f*)(out + o) = r;
}

extern "C" void kernel_launch(void* const* d_in, const int* in_sizes, int n_in,
                              void* d_out, int out_size, void* d_ws, size_t ws_size,
                              hipStream_t stream) {
    const float* x    = (const float*)d_in[0];
    const float* Wq   = (const float*)d_in[1];
    const float* Wk   = (const float*)d_in[2];
    const float* Wv   = (const float*)d_in[3];
    const float* Wout = (const float*)d_in[4];
    float* out = (float*)d_out;
    float* ws  = (float*)d_ws;

    // ws layout (floats): qv [B][N][16] | kb [B][8][N] | attab [B][9][N]
    float* qv    = ws;
    float* kb    = ws + (size_t)BB * NN * 16;
    float* attab = kb + (size_t)BB * CI * NN;

    qkv_kernel<<<dim3(NN / 32, BB), 256, 0, stream>>>(x, Wq, Wk, Wv, qv, kb, attab);
    att_kernel<<<dim3(NN / (256 * MT), NN / NCHUNK, BB), 256, 0, stream>>>(qv, kb, attab);
    out_kernel<<<dim3(NN / 1024, CC, BB), 256, 0, stream>>>(x, Wout, attab, out);
}